// Round 1
// baseline (348.470 us; speedup 1.0000x reference)
//
#include <hip/hip_runtime.h>
#include <math.h>

#define IMG_H 8192
#define IMG_W 8192
#define PATCH 32
#define HP 256
#define WP 256
#define NPATCH (HP * WP)   // 65536

__device__ __constant__ float c_MU  = 0.34f;
__device__ __constant__ float c_INV_STD = 25.0f;            // 1/0.04
__device__ __constant__ float c_LOG_NORM_CONST = -2.2999373f; // log(0.04*sqrt(2*pi))

// ---------------------------------------------------------------------------
// Kernel 1: per-patch mean. One wave (64 lanes) per 32x32 patch.
// Lane layout per iteration i (i=0..3): rows i*8 + (lane>>3), float4 col (lane&7).
// Each 8-lane group reads 128 contiguous, 128B-aligned bytes -> full cache lines.
// ---------------------------------------------------------------------------
__global__ __launch_bounds__(256) void patch_mean_kernel(
    const float* __restrict__ x, float* __restrict__ means)
{
    const int wave  = threadIdx.x >> 6;          // 0..3
    const int lane  = threadIdx.x & 63;
    const int patch = blockIdx.x * 4 + wave;     // one patch per wave
    const int ph = patch >> 8;                   // 0..255
    const int pw = patch & 255;                  // 0..255

    const float* base = x + (size_t)(ph * PATCH) * IMG_W + (size_t)(pw * PATCH);
    const int r0 = lane >> 3;    // 0..7
    const int cv = lane & 7;     // float4 index within row segment

    float s = 0.0f;
#pragma unroll
    for (int i = 0; i < 4; ++i) {
        const float4 v = *reinterpret_cast<const float4*>(
            base + (size_t)(i * 8 + r0) * IMG_W + cv * 4);
        s += (v.x + v.y) + (v.z + v.w);
    }

    // wave-64 reduction
#pragma unroll
    for (int off = 32; off >= 1; off >>= 1)
        s += __shfl_down(s, off, 64);

    if (lane == 0)
        means[patch] = s * (1.0f / 1024.0f);
}

// ---------------------------------------------------------------------------
// Kernel 2: masked pos/neg partial sums over the 65536 patch means.
// 64 blocks x 256 threads, 4 elements (float4) per thread.
// acc[0]=pos_sum, acc[1]=neg_sum, acc[2]=pos_cnt
// ---------------------------------------------------------------------------
__global__ __launch_bounds__(256) void loss_partial_kernel(
    const float* __restrict__ means, const float* __restrict__ tmask,
    float* __restrict__ acc)
{
    const int idx = (blockIdx.x * 256 + threadIdx.x) * 4;

    const float4 m4 = *reinterpret_cast<const float4*>(means + idx);
    const float4 t4 = *reinterpret_cast<const float4*>(tmask + idx);

    const float mv[4] = { m4.x, m4.y, m4.z, m4.w };
    const float tv[4] = { t4.x, t4.y, t4.z, t4.w };

    float pos = 0.0f, neg = 0.0f, cnt = 0.0f;
#pragma unroll
    for (int i = 0; i < 4; ++i) {
        const float z = (mv[i] - c_MU) * c_INV_STD;
        const float logpdf = -0.5f * z * z - c_LOG_NORM_CONST;
        const float pterm = -logf(expf(logpdf) + 1e-6f);
        const float nterm = mv[i] * mv[i];
        if (tv[i] >= 0.5f) { pos += pterm; cnt += 1.0f; }
        else               { neg += nterm; }
    }

    // wave reduce
#pragma unroll
    for (int off = 32; off >= 1; off >>= 1) {
        pos += __shfl_down(pos, off, 64);
        neg += __shfl_down(neg, off, 64);
        cnt += __shfl_down(cnt, off, 64);
    }

    __shared__ float s_pos[4], s_neg[4], s_cnt[4];
    const int wave = threadIdx.x >> 6;
    const int lane = threadIdx.x & 63;
    if (lane == 0) { s_pos[wave] = pos; s_neg[wave] = neg; s_cnt[wave] = cnt; }
    __syncthreads();

    if (threadIdx.x == 0) {
        float bp = s_pos[0] + s_pos[1] + s_pos[2] + s_pos[3];
        float bn = s_neg[0] + s_neg[1] + s_neg[2] + s_neg[3];
        float bc = s_cnt[0] + s_cnt[1] + s_cnt[2] + s_cnt[3];
        atomicAdd(&acc[0], bp);
        atomicAdd(&acc[1], bn);
        atomicAdd(&acc[2], bc);
    }
}

// ---------------------------------------------------------------------------
// Kernel 3: finalize scalar.
// ---------------------------------------------------------------------------
__global__ void finalize_kernel(const float* __restrict__ acc, float* __restrict__ out)
{
    const float pos_cnt = acc[2];
    const float neg_cnt = (float)NPATCH - pos_cnt;
    out[0] = acc[0] / pos_cnt + acc[1] / neg_cnt;
}

extern "C" void kernel_launch(void* const* d_in, const int* in_sizes, int n_in,
                              void* d_out, int out_size, void* d_ws, size_t ws_size,
                              hipStream_t stream)
{
    const float* unet  = (const float*)d_in[0];   // [1,1,8192,8192] fp32
    const float* trans = (const float*)d_in[1];   // [1,256,256] fp32
    float* out = (float*)d_out;                   // scalar fp32

    float* means = (float*)d_ws;                  // 65536 floats
    float* acc   = means + NPATCH;                // 3 floats

    hipMemsetAsync(acc, 0, 3 * sizeof(float), stream);

    // 65536 patches, 4 per block (one per wave)
    patch_mean_kernel<<<NPATCH / 4, 256, 0, stream>>>(unet, means);

    // 65536 means, 1024 per block
    loss_partial_kernel<<<NPATCH / 1024, 256, 0, stream>>>(means, trans, acc);

    finalize_kernel<<<1, 1, 0, stream>>>(acc, out);
}